// Round 12
// baseline (215.137 us; speedup 1.0000x reference)
//
#include <hip/hip_runtime.h>
#include <math.h>

#define B_DIM 4
#define L_DIM 8192
#define H_DIM 256
#define P_DIM 256
#define M_DIM (B_DIM * L_DIM)   // 32768 rows (b,l) flattened
#define NC 64                   // scan chunks per chain (chunk = 128 rows = one k1 tile)
#define LC 128                  // chunk length

typedef __attribute__((ext_vector_type(8))) short bf16x8;
typedef __attribute__((ext_vector_type(4))) float f32x4;

static __device__ __forceinline__ float bf2f(unsigned int u) {
    union { unsigned int i; float f; } v; v.i = u << 16; return v.f;
}
static __device__ __forceinline__ float bits2f(unsigned int u) {
    union { unsigned int i; float f; } v; v.i = u; return v.f;
}
static __device__ __forceinline__ unsigned short f2bf(float f) {
    union { float f; unsigned int i; } v; v.f = f;
    unsigned int r = v.i + 0x7FFFu + ((v.i >> 16) & 1u);
    return (unsigned short)(r >> 16);
}
// pack two f32 -> one u32 of {lo: bf16(x), hi: bf16(y)} -- pure integer RNE (deterministic,
// no HW mode dependence). NOTE: v_cvt_pk_bf16_f32 was tried (r7/r8) and caused
// replay-to-replay output drift (r9 bisect); keep the integer path.
static __device__ __forceinline__ unsigned int pack_bf16i(float x, float y) {
    return (unsigned int)f2bf(x) | ((unsigned int)f2bf(y) << 16);
}
// tanh-form GELU; |gelu_tanh - gelu_erf| <= ~0.003 absolute, far under threshold
static __device__ __forceinline__ float gelu_f(float x) {
    float z = 0.7978845608028654f * (x + 0.044715f * x * x * x);
    float e = __expf(2.0f * z);
    float t = 1.0f - 2.0f / (e + 1.0f);   // tanh(z)
    return 0.5f * x * (1.0f + t);
}
// async global->LDS DMA, 16B per lane; LDS dest = base + lane*16 (wave-uniform base)
static __device__ __forceinline__ void async_load16(const void* g, void* l) {
    __builtin_amdgcn_global_load_lds(
        (const __attribute__((address_space(1))) unsigned int*)g,
        (__attribute__((address_space(3))) unsigned int*)l, 16, 0, 0);
}
// complex helpers
static __device__ __forceinline__ float2 cmul2(float2 a, float2 b) {
    return make_float2(a.x * b.x - a.y * b.y, a.x * b.y + a.y * b.x);
}
static __device__ __forceinline__ float2 csq2(float2 a) {
    return make_float2(a.x * a.x - a.y * a.y, 2.f * a.x * a.y);
}
// A*s + z
static __device__ __forceinline__ float2 cmad(float2 A, float2 s, float2 z) {
    return make_float2(A.x * s.x - A.y * s.y + z.x, A.x * s.y + A.y * s.x + z.y);
}

// ---------------- combined prep + xcast kernel ----------------
__global__ void prep_kernel(const float* fLr, const float* fIm, const float* fLd,
                            const float* fBr, const float* fBi,
                            const float* fCr, const float* fCi,
                            const float* bLr, const float* bIm, const float* bLd,
                            const float* bBr, const float* bBi,
                            const float* bCr, const float* bCi,
                            const float4* __restrict__ x4, ushort4* __restrict__ xb,
                            unsigned short* Bmat, unsigned short* B3, float2* LbarWS) {
    int gid = blockIdx.x * 256 + threadIdx.x;
    if (gid < 2097152) {
        float4 v = x4[gid];
        ushort4 o;
        o.x = f2bf(v.x); o.y = f2bf(v.y); o.z = f2bf(v.z); o.w = f2bf(v.w);
        xb[gid] = o;
        return;
    }
    int g1 = gid - 2097152;
    if (g1 < 262144) {
        // Bmat
        int k = g1 >> 8, h = g1 & 255;
        int d = k >> 9, pc = k & 511, p = pc >> 1, comp = pc & 1;
        const float* LR = d ? bLr : fLr;
        const float* IM = d ? bIm : fIm;
        const float* LD = d ? bLd : fLd;
        const float* BR = d ? bBr : fBr;
        const float* BI = d ? bBi : fBi;
        float Lr = -expf(LR[p]);
        float Li = IM[p];
        float Delta = expf(LD[p]);
        float ea = expf(Lr * Delta);
        float bd = Li * Delta;
        float Lbr = ea * cosf(bd);
        float Lbi = ea * sinf(bd);
        float denom = fmaxf(Lr * Lr + Li * Li, 1e-12f);
        float ivr = Lr / denom, ivi = -Li / denom;
        float dr = Lbr - 1.0f, di = Lbi;
        float cr = ivr * dr - ivi * di;
        float ci = ivr * di + ivi * dr;
        float br = BR[p * 256 + h], bi = BI[p * 256 + h];
        float val = comp ? (cr * bi + ci * br) : (cr * br - ci * bi);
        Bmat[g1] = f2bf(val);
    } else if (g1 < 524288) {
        int g2 = g1 - 262144;
        int d = g2 >> 17;
        int rem = g2 & 131071;
        int h = rem >> 9;
        int kk = rem & 511;
        int p = kk >> 1, comp = kk & 1;
        const float* CR = d ? bCr : fCr;
        const float* CI = d ? bCi : fCi;
        float val = comp ? -CI[h * 256 + p] : CR[h * 256 + p];
        B3[g2] = f2bf(val);
    } else if (g1 < 524800) {
        int g2 = g1 - 524288;          // 0..511
        int d = g2 >> 8, p = g2 & 255;
        const float* LR = d ? bLr : fLr;
        const float* IM = d ? bIm : fIm;
        const float* LD = d ? bLd : fLd;
        float Lr = -expf(LR[p]); float Li = IM[p]; float Delta = expf(LD[p]);
        float ea = expf(Lr * Delta); float bd = Li * Delta;
        LbarWS[g2] = make_float2(ea * cosf(bd), ea * sinf(bd));
    }
}

// ---------------- K1: Bu = xbf(32768x256) @ Bmat(1024x256)^T -> Bu bf16 (32768x1024) ----------------
// Epilogue: C tile -> LDS -> coalesced Bu store (UNFIXED z-values) + fused per-chunk scan:
// full-chunk carry and 8 sub-chunk partial states U(c,q) per chain.
__global__ __launch_bounds__(256, 2) void k1_gemm(const unsigned short* __restrict__ A,
                                                  const unsigned short* __restrict__ Bm,
                                                  unsigned short* __restrict__ Bu,
                                                  const float2* __restrict__ Lbar,
                                                  float2* __restrict__ carry,
                                                  float2* __restrict__ Usub) {
    __shared__ unsigned short SH[16384];   // 32 KB: As=SH[0:8192], Bs=SH[8192:16384]; Cs overlays all
    __shared__ float2 Sbuf2[64][4];        // half-1 snapshots (3) + final (1) per chain
    int tid = threadIdx.x;
    int lane = tid & 63, wv = tid >> 6;          // 4 waves
    int wm = (wv >> 1) * 64, wn = (wv & 1) * 64; // 64x64 quadrant
    int Mb = blockIdx.x * 128, Nb = blockIdx.y * 128;
    int lr = lane >> 3;                 // row within 8-row chunk group
    int swz = ((lane & 7) ^ lr) * 8;    // swizzled source chunk (in shorts)
    f32x4 acc[4][4];
#pragma unroll
    for (int i = 0; i < 4; i++)
#pragma unroll
        for (int j = 0; j < 4; j++) acc[i][j] = (f32x4){0.f, 0.f, 0.f, 0.f};
    int mrow = lane & 15, quad = lane >> 4;
    for (int kb = 0; kb < 256; kb += 64) {
#pragma unroll
        for (int ch = wv; ch < 16; ch += 4) {
            int r = ch * 8 + lr;
            async_load16(A  + (size_t)(Mb + r) * 256 + kb + swz, (char*)SH + ch * 1024);
            async_load16(Bm + (size_t)(Nb + r) * 256 + kb + swz, (char*)SH + 16384 + ch * 1024);
        }
        __syncthreads();
#pragma unroll
        for (int kk = 0; kk < 64; kk += 32) {
            bf16x8 af[4], bfr[4];
#pragma unroll
            for (int i = 0; i < 4; i++) {
                int rr = wm + 16 * i + mrow;
                af[i] = *(const bf16x8*)&SH[rr * 64 + ((((kk >> 3) + quad) ^ (rr & 7)) << 3)];
            }
#pragma unroll
            for (int j = 0; j < 4; j++) {
                int rr = wn + 16 * j + mrow;
                bfr[j] = *(const bf16x8*)&SH[8192 + rr * 64 + ((((kk >> 3) + quad) ^ (rr & 7)) << 3)];
            }
#pragma unroll
            for (int i = 0; i < 4; i++)
#pragma unroll
                for (int j = 0; j < 4; j++)
                    acc[i][j] = __builtin_amdgcn_mfma_f32_16x16x32_bf16(af[i], bfr[j], acc[i][j], 0, 0, 0);
        }
        __syncthreads();
    }
    // ---- epilogue: C tile (128x128 bf16) into LDS ----
    unsigned short* Cs = SH;
#pragma unroll
    for (int i = 0; i < 4; i++)
#pragma unroll
        for (int j = 0; j < 4; j++)
#pragma unroll
            for (int r = 0; r < 4; r++) {
                int row = wm + 16 * i + quad * 4 + r;
                int col = wn + 16 * j + mrow;
                Cs[row * 128 + col] = f2bf(acc[i][j][r]);
            }
    __syncthreads();
    // coalesced Cs -> Bu (uint4 per thread, 8 iters) -- UNFIXED values
#pragma unroll
    for (int it = 0; it < 8; it++) {
        int o = tid * 16 + it * 4096;       // byte offset in Cs
        int row = o >> 8, colb = o & 255;
        uint4 v = *(const uint4*)((const char*)Cs + o);
        *(uint4*)((char*)Bu + (size_t)(Mb + row) * 2048 + (size_t)Nb * 2 + colb) = v;
    }
    // fused per-chunk scan: this block is chunk c of batch b, 64 complex chains.
    int d = Nb >> 9;
    int b = Mb >> 13;
    int c = (Mb >> 7) & 63;
    float2 s = make_float2(0.f, 0.f);
    float2 A2 = make_float2(0.f, 0.f);
    float2 snap[3];
    snap[0] = snap[1] = snap[2] = make_float2(0.f, 0.f);
    int p = 0;
    if (tid < 128) {
        int j = tid & 63, half = tid >> 6;
        p = ((Nb & 511) >> 1) + j;
        A2 = Lbar[d * 256 + p];
        const unsigned int* C32 = (const unsigned int*)Cs;
        int r0 = half * 64;
        if (d == 0) {
            for (int t = 0; t < 64; t++) {
                unsigned int v = C32[(r0 + t) * 64 + j];
                float2 z = make_float2(bf2f(v & 0xffffu), bf2f(v >> 16));
                s = cmad(A2, s, z);
                if ((t & 15) == 15 && t < 63) snap[t >> 4] = s;   // t=15,31,47 -> snap[0..2]
            }
        } else {
            for (int t = 63; t >= 0; t--) {
                unsigned int v = C32[(r0 + t) * 64 + j];
                float2 z = make_float2(bf2f(v & 0xffffu), bf2f(v >> 16));
                s = cmad(A2, s, z);
                if ((t & 15) == 0 && t > 0) snap[(t >> 4) - 1] = s;  // t=48,32,16 -> snap[2,1,0]
            }
        }
        if (half == 1) {
            Sbuf2[j][0] = snap[0]; Sbuf2[j][1] = snap[1];
            Sbuf2[j][2] = snap[2]; Sbuf2[j][3] = s;
        }
    }
    __syncthreads();
    if (tid < 64) {
        // own (half-0) state: fwd S0 (rows 0..63) / bwd S0' (rows 63..0 desc)
        float2 h1a = Sbuf2[tid][0], h1b = Sbuf2[tid][1], h1c = Sbuf2[tid][2], S1 = Sbuf2[tid][3];
        float2 a16 = A2;
#pragma unroll
        for (int k = 0; k < 4; k++) a16 = csq2(a16);
        float2 a32 = csq2(a16);
        float2 a48 = cmul2(a32, a16);
        float2 a64 = csq2(a32);
        float2 S0 = s;
        float2 Uq[8];
        float2 cfull;
        float2 zero = make_float2(0.f, 0.f);
        if (d == 0) {
            // U(q) = zero-init scan of rows [0,16q)
            Uq[0] = zero;  Uq[1] = snap[0]; Uq[2] = snap[1]; Uq[3] = snap[2];
            Uq[4] = S0;
            Uq[5] = cmad(a16, S0, h1a);   // rows[0,80)
            Uq[6] = cmad(a32, S0, h1b);
            Uq[7] = cmad(a48, S0, h1c);
            cfull = cmad(a64, S0, S1);
        } else {
            // bwd processes rows 127..0; U'(q) = zero-init scan of rows [16q+16,128)
            Uq[7] = zero;
            Uq[6] = h1c;   // rows[112,128)
            Uq[5] = h1b;   // rows[96,128)
            Uq[4] = h1a;   // rows[80,128)
            Uq[3] = S1;    // rows[64,128)
            Uq[2] = cmad(a16, S1, snap[2]);  // + rows[48,64)
            Uq[1] = cmad(a32, S1, snap[1]);
            Uq[0] = cmad(a48, S1, snap[0]);
            cfull = cmad(a64, S1, S0);
        }
        size_t cidx = ((size_t)(d * 4 + b) * NC + c) * 256 + p;
        carry[cidx] = cfull;
        size_t ub = (((size_t)(d * 4 + b) * NC + c) * 8) * 256 + p;
#pragma unroll
        for (int q = 0; q < 8; q++) Usub[ub + (size_t)q * 256] = Uq[q];
    }
}

// ---------------- K3 half: one K=512 GEMM, r9-verbatim (single-buffered BK=64,
// 3x __syncthreads per stage, no DMA crossing a barrier interval, integer pack,
// U via register, A^16 from LDS table). ----------------
static __device__ __forceinline__ void k3_half(const unsigned short* __restrict__ XS,
                                               const unsigned short* __restrict__ B3h,
                                               unsigned short* As, unsigned short* Bs,
                                               const float2* Ptab, const float2* LbarL,
                                               const float2* La16L,
                                               const float2* __restrict__ Uchunk,
                                               int Mb, int Hb, int coff, int d,
                                               int wm, int wn, int mrow, int quad,
                                               int lr, int swz, int wv, int tid,
                                               f32x4 (&acc)[4][4]) {
    int j = tid & 31, q = tid >> 5;
    int r0 = q * 16;
    const float2* ubase = Uchunk + q * 256 + j;   // U(q, p=(kb>>1)+j) = ubase[kb>>1]
    for (int st = 0; st < 8; st++) {
        int kb = st * 64;
        // ---- issue this stage's DMA (prev stage's MFMA reads ordered by trailing sync) ----
#pragma unroll
        for (int ch = wv; ch < 16; ch += 4) {
            int r = ch * 8 + lr;
            async_load16(XS + (size_t)(Mb + r) * 1024 + coff + kb + swz, (char*)As + ch * 1024);
            async_load16(B3h + (size_t)(Hb + r) * 512 + kb + swz, (char*)Bs + ch * 1024);
        }
        float2 Ucur = ubase[kb >> 1];   // L2-resident global load (drained by sync)
        __syncthreads();   // tile ready for ALL waves (full vmcnt+lgkm drain + barrier)
        // ---- scan-fix the staged A tile ----
        {
            int p = (kb >> 1) + j;
            float2 Ach = LbarL[d * 256 + p];
            float2 P  = Ptab[d * 256 + p];
            int e = d ? (7 - q) : q;        // rows already processed = 16*e
            float2 bp = La16L[d * 256 + p];  // A^16 (precomputed during prefix)
            float2 ap = make_float2(1.f, 0.f);
            if (e & 1) ap = cmul2(ap, bp);
            bp = csq2(bp);                   // A^32
            if (e & 2) ap = cmul2(ap, bp);
            bp = csq2(bp);                   // A^64
            if (e & 4) ap = cmul2(ap, bp);
            float2 sv = cmad(ap, P, Ucur);  // entering state for this sub-block
            unsigned int* A32 = (unsigned int*)As;
            unsigned int zb[16];
#pragma unroll
            for (int tt = 0; tt < 16; tt++) {
                int row = r0 + tt;
                zb[tt] = A32[row * 32 + (((j >> 2) ^ (row & 7)) << 2) + (j & 3)];
            }
            if (d == 0) {
#pragma unroll
                for (int tt = 0; tt < 16; tt++) {
                    float2 z = make_float2(bits2f(zb[tt] << 16), bits2f(zb[tt] & 0xffff0000u));
                    sv = cmad(Ach, sv, z);
                    zb[tt] = pack_bf16i(sv.x, sv.y);
                }
            } else {
#pragma unroll
                for (int tt = 15; tt >= 0; tt--) {
                    float2 z = make_float2(bits2f(zb[tt] << 16), bits2f(zb[tt] & 0xffff0000u));
                    sv = cmad(Ach, sv, z);
                    zb[tt] = pack_bf16i(sv.x, sv.y);
                }
            }
#pragma unroll
            for (int tt = 0; tt < 16; tt++) {
                int row = r0 + tt;
                A32[row * 32 + (((j >> 2) ^ (row & 7)) << 2) + (j & 3)] = zb[tt];
            }
        }
        __syncthreads();   // fix visible to all waves
        // ---- MFMA on fixed tile ----
#pragma unroll
        for (int kk = 0; kk < 64; kk += 32) {
            bf16x8 af[4], bfr[4];
#pragma unroll
            for (int i = 0; i < 4; i++) {
                int rr = wm + 16 * i + mrow;
                af[i] = *(const bf16x8*)&As[rr * 64 + ((((kk >> 3) + quad) ^ (rr & 7)) << 3)];
            }
#pragma unroll
            for (int jj2 = 0; jj2 < 4; jj2++) {
                int rr = wn + 16 * jj2 + mrow;
                bfr[jj2] = *(const bf16x8*)&Bs[rr * 64 + ((((kk >> 3) + quad) ^ (rr & 7)) << 3)];
            }
#pragma unroll
            for (int i = 0; i < 4; i++)
#pragma unroll
                for (int jj2 = 0; jj2 < 4; jj2++)
                    acc[i][jj2] = __builtin_amdgcn_mfma_f32_16x16x32_bf16(af[i], bfr[jj2], acc[i][jj2], 0, 0, 0);
        }
        __syncthreads();   // MFMA reads done before next stage's DMA overwrites
    }
}

// ---------------- K3: out = gelu(xs_f·Cf + Df*x) + gelu(xs_b·Cb + Db*x), fused scan fix ----------------
// Occupancy build v2: ONE acc[4][4] reused across the two sequential K=512 halves; the fwd
// result yf = gelu(accf + Df*x) is written to `out` in FULL F32 (exact stash -- r11's bf16
// stash cost +0.078 absmax and failed), acc zeroed, bwd half runs, final epilogue does
// out += gelu(accb + Db*x). Same-thread global RMW only (compiler-ordered). Arithmetic
// values/order bit-identical to r9. Register footprint ~64 acc + arch ->
// __launch_bounds__(256,3) = 3 blocks/CU (LDS 44KB x3 = 132 <= 160).
__global__ __launch_bounds__(256, 3) void k3_gemm(const unsigned short* __restrict__ XS,
                                                  const unsigned short* __restrict__ B3,
                                                  const unsigned short* __restrict__ xbf,
                                                  const float* __restrict__ Df,
                                                  const float* __restrict__ Db,
                                                  const float2* __restrict__ Lbar,
                                                  const float2* __restrict__ carry,
                                                  const float2* __restrict__ Usub,
                                                  float* __restrict__ out) {
    __shared__ unsigned short As[8192], Bs[8192];   // 16 KB single-buffered tiles
    __shared__ float2 Ptab[512];    // chunk-entry prefix states (d*256+p)
    __shared__ float2 LbarL[512];
    __shared__ float2 La16L[512];   // A^16 per (d,p) -- captured mid-prefix for free
    int tid = threadIdx.x;
    int lane = tid & 63, wv = tid >> 6;          // 4 waves
    int wm = (wv >> 1) * 64, wn = (wv & 1) * 64; // 64x64 quadrant
    int Mb = blockIdx.x * 128, Hb = blockIdx.y * 128;
    int b = Mb >> 13, c = (Mb >> 7) & 63;
    int lr = lane >> 3;
    int swz = ((lane & 7) ^ lr) * 8;
    int mrow = lane & 15, quad = lane >> 4;
    // ---- chunk-entry prefix: combine <=63 chunk carries (L2-resident, loads pipelined) ----
    {
        int p0 = tid;
#pragma unroll
        for (int d2 = 0; d2 < 2; d2++) {
            float2 A = Lbar[d2 * 256 + p0];
            LbarL[d2 * 256 + p0] = A;
            float2 apow = A;
#pragma unroll
            for (int k = 0; k < 4; k++) apow = csq2(apow);   // A^16
            La16L[d2 * 256 + p0] = apow;
#pragma unroll
            for (int k = 0; k < 3; k++) apow = csq2(apow);   // A^128
            float2 a128 = apow;
            float2 s = make_float2(0.f, 0.f);
            const float2* cb = carry + ((size_t)(d2 * 4 + b) * NC) * 256 + p0;
            if (d2 == 0) {
#pragma unroll 16
                for (int jj = 0; jj < c; jj++) s = cmad(a128, s, cb[(size_t)jj * 256]);
            } else {
#pragma unroll 16
                for (int jj = NC - 1; jj > c; jj--) s = cmad(a128, s, cb[(size_t)jj * 256]);
            }
            Ptab[d2 * 256 + p0] = s;
        }
    }
    __syncthreads();
    f32x4 acc[4][4];
#pragma unroll
    for (int i = 0; i < 4; i++)
#pragma unroll
        for (int j = 0; j < 4; j++) acc[i][j] = (f32x4){0.f, 0.f, 0.f, 0.f};
    const float2* U0 = Usub + (((size_t)(0 * 4 + b) * NC + c) * 8) * 256;
    const float2* U1 = Usub + (((size_t)(1 * 4 + b) * NC + c) * 8) * 256;
    // ---- forward half (k-cols 0..511) ----
    k3_half(XS, B3, As, Bs, Ptab, LbarL, La16L, U0, Mb, Hb, 0, 0,
            wm, wn, mrow, quad, lr, swz, wv, tid, acc);
    // ---- mid-epilogue: out = gelu(acc + Df*x) in full f32 (exact stash in out) ----
#pragma unroll
    for (int i = 0; i < 4; i++)
#pragma unroll
        for (int j = 0; j < 4; j++) {
            int h = Hb + wn + 16 * j + mrow;
            float df = Df[h];
#pragma unroll
            for (int r = 0; r < 4; r++) {
                int row = Mb + wm + 16 * i + quad * 4 + r;
                float xv = bf2f((unsigned int)xbf[(size_t)row * 256 + h]);
                out[(size_t)row * 256 + h] = gelu_f(acc[i][j][r] + df * xv);
            }
            acc[i][j] = (f32x4){0.f, 0.f, 0.f, 0.f};
        }
    // ---- backward half (k-cols 512..1023) ----
    k3_half(XS, B3 + 131072, As, Bs, Ptab, LbarL, La16L, U1, Mb, Hb, 512, 1,
            wm, wn, mrow, quad, lr, swz, wv, tid, acc);
    // ---- final epilogue: out += gelu(acc + Db*x) (same-thread RMW, exact) ----
#pragma unroll
    for (int i = 0; i < 4; i++)
#pragma unroll
        for (int j = 0; j < 4; j++) {
            int h = Hb + wn + 16 * j + mrow;
            float db = Db[h];
#pragma unroll
            for (int r = 0; r < 4; r++) {
                int row = Mb + wm + 16 * i + quad * 4 + r;
                float xv = bf2f((unsigned int)xbf[(size_t)row * 256 + h]);
                size_t oi = (size_t)row * 256 + h;
                out[oi] = out[oi] + gelu_f(acc[i][j][r] + db * xv);
            }
        }
}

// ---------------- launcher ----------------
extern "C" void kernel_launch(void* const* d_in, const int* in_sizes, int n_in,
                              void* d_out, int out_size, void* d_ws, size_t ws_size,
                              hipStream_t stream) {
    const float* x   = (const float*)d_in[0];
    const float* fLr = (const float*)d_in[1];
    const float* fIm = (const float*)d_in[2];
    const float* fLd = (const float*)d_in[3];
    const float* fBr = (const float*)d_in[4];
    const float* fBi = (const float*)d_in[5];
    const float* fCr = (const float*)d_in[6];
    const float* fCi = (const float*)d_in[7];
    const float* fD  = (const float*)d_in[8];
    const float* bLr = (const float*)d_in[9];
    const float* bIm = (const float*)d_in[10];
    const float* bLd = (const float*)d_in[11];
    const float* bBr = (const float*)d_in[12];
    const float* bBi = (const float*)d_in[13];
    const float* bCr = (const float*)d_in[14];
    const float* bCi = (const float*)d_in[15];
    const float* bD  = (const float*)d_in[16];
    float* out = (float*)d_out;

    char* ws = (char*)d_ws;
    unsigned short* xbf  = (unsigned short*)(ws);                               // 16 MiB
    unsigned short* Bu   = (unsigned short*)(ws + 16777216);                    // 64 MiB (unfixed z)
    unsigned short* Bmat = (unsigned short*)(ws + 16777216 + 67108864);         // 512 KiB
    unsigned short* B3   = (unsigned short*)(ws + 16777216 + 67108864 + 524288);// 512 KiB
    float2* LbarWS = (float2*)(ws + 16777216 + 67108864 + 1048576);             // 4 KiB
    float2* carry  = (float2*)(ws + 16777216 + 67108864 + 1048576 + 4096);      // 1 MiB
    float2* Usub   = (float2*)(ws + 16777216 + 67108864 + 1048576 + 4096 + 1048576); // 8 MiB

    prep_kernel<<<10242, 256, 0, stream>>>(fLr, fIm, fLd, fBr, fBi, fCr, fCi,
                                           bLr, bIm, bLd, bBr, bBi, bCr, bCi,
                                           (const float4*)x, (ushort4*)xbf,
                                           Bmat, B3, LbarWS);
    k1_gemm<<<dim3(256, 8), 256, 0, stream>>>(xbf, Bmat, Bu, LbarWS, carry, Usub);
    k3_gemm<<<dim3(256, 2), 256, 0, stream>>>(Bu, B3, xbf, fD, bD, LbarWS, carry, Usub, out);
}

// Round 14
// 192.531 us; speedup vs baseline: 1.1174x; 1.1174x over previous
//
#include <hip/hip_runtime.h>
#include <math.h>

#define B_DIM 4
#define L_DIM 8192
#define H_DIM 256
#define P_DIM 256
#define M_DIM (B_DIM * L_DIM)   // 32768 rows (b,l) flattened
#define NC 64                   // scan chunks per chain (chunk = 128 rows = one k1 tile)
#define LC 128                  // chunk length

typedef __attribute__((ext_vector_type(8))) short bf16x8;
typedef __attribute__((ext_vector_type(4))) float f32x4;

static __device__ __forceinline__ float bf2f(unsigned int u) {
    union { unsigned int i; float f; } v; v.i = u << 16; return v.f;
}
static __device__ __forceinline__ float bits2f(unsigned int u) {
    union { unsigned int i; float f; } v; v.i = u; return v.f;
}
static __device__ __forceinline__ unsigned short f2bf(float f) {
    union { float f; unsigned int i; } v; v.f = f;
    unsigned int r = v.i + 0x7FFFu + ((v.i >> 16) & 1u);
    return (unsigned short)(r >> 16);
}
// pack two f32 -> one u32 of {lo: bf16(x), hi: bf16(y)} -- pure integer RNE (deterministic,
// no HW mode dependence). NOTE: v_cvt_pk_bf16_f32 was tried (r7/r8) and caused
// replay-to-replay output drift (r9 bisect); keep the integer path.
static __device__ __forceinline__ unsigned int pack_bf16i(float x, float y) {
    return (unsigned int)f2bf(x) | ((unsigned int)f2bf(y) << 16);
}
// tanh-form GELU; |gelu_tanh - gelu_erf| <= ~0.003 absolute, far under threshold
static __device__ __forceinline__ float gelu_f(float x) {
    float z = 0.7978845608028654f * (x + 0.044715f * x * x * x);
    float e = __expf(2.0f * z);
    float t = 1.0f - 2.0f / (e + 1.0f);   // tanh(z)
    return 0.5f * x * (1.0f + t);
}
// async global->LDS DMA, 16B per lane; LDS dest = base + lane*16 (wave-uniform base)
static __device__ __forceinline__ void async_load16(const void* g, void* l) {
    __builtin_amdgcn_global_load_lds(
        (const __attribute__((address_space(1))) unsigned int*)g,
        (__attribute__((address_space(3))) unsigned int*)l, 16, 0, 0);
}
// complex helpers
static __device__ __forceinline__ float2 cmul2(float2 a, float2 b) {
    return make_float2(a.x * b.x - a.y * b.y, a.x * b.y + a.y * b.x);
}
static __device__ __forceinline__ float2 csq2(float2 a) {
    return make_float2(a.x * a.x - a.y * a.y, 2.f * a.x * a.y);
}
// A*s + z
static __device__ __forceinline__ float2 cmad(float2 A, float2 s, float2 z) {
    return make_float2(A.x * s.x - A.y * s.y + z.x, A.x * s.y + A.y * s.x + z.y);
}

// ---------------- combined prep + xcast kernel ----------------
__global__ void prep_kernel(const float* fLr, const float* fIm, const float* fLd,
                            const float* fBr, const float* fBi,
                            const float* fCr, const float* fCi,
                            const float* bLr, const float* bIm, const float* bLd,
                            const float* bBr, const float* bBi,
                            const float* bCr, const float* bCi,
                            const float4* __restrict__ x4, ushort4* __restrict__ xb,
                            unsigned short* Bmat, unsigned short* B3, float2* LbarWS) {
    int gid = blockIdx.x * 256 + threadIdx.x;
    if (gid < 2097152) {
        float4 v = x4[gid];
        ushort4 o;
        o.x = f2bf(v.x); o.y = f2bf(v.y); o.z = f2bf(v.z); o.w = f2bf(v.w);
        xb[gid] = o;
        return;
    }
    int g1 = gid - 2097152;
    if (g1 < 262144) {
        // Bmat
        int k = g1 >> 8, h = g1 & 255;
        int d = k >> 9, pc = k & 511, p = pc >> 1, comp = pc & 1;
        const float* LR = d ? bLr : fLr;
        const float* IM = d ? bIm : fIm;
        const float* LD = d ? bLd : fLd;
        const float* BR = d ? bBr : fBr;
        const float* BI = d ? bBi : fBi;
        float Lr = -expf(LR[p]);
        float Li = IM[p];
        float Delta = expf(LD[p]);
        float ea = expf(Lr * Delta);
        float bd = Li * Delta;
        float Lbr = ea * cosf(bd);
        float Lbi = ea * sinf(bd);
        float denom = fmaxf(Lr * Lr + Li * Li, 1e-12f);
        float ivr = Lr / denom, ivi = -Li / denom;
        float dr = Lbr - 1.0f, di = Lbi;
        float cr = ivr * dr - ivi * di;
        float ci = ivr * di + ivi * dr;
        float br = BR[p * 256 + h], bi = BI[p * 256 + h];
        float val = comp ? (cr * bi + ci * br) : (cr * br - ci * bi);
        Bmat[g1] = f2bf(val);
    } else if (g1 < 524288) {
        int g2 = g1 - 262144;
        int d = g2 >> 17;
        int rem = g2 & 131071;
        int h = rem >> 9;
        int kk = rem & 511;
        int p = kk >> 1, comp = kk & 1;
        const float* CR = d ? bCr : fCr;
        const float* CI = d ? bCi : fCi;
        float val = comp ? -CI[h * 256 + p] : CR[h * 256 + p];
        B3[g2] = f2bf(val);
    } else if (g1 < 524800) {
        int g2 = g1 - 524288;          // 0..511
        int d = g2 >> 8, p = g2 & 255;
        const float* LR = d ? bLr : fLr;
        const float* IM = d ? bIm : fIm;
        const float* LD = d ? bLd : fLd;
        float Lr = -expf(LR[p]); float Li = IM[p]; float Delta = expf(LD[p]);
        float ea = expf(Lr * Delta); float bd = Li * Delta;
        LbarWS[g2] = make_float2(ea * cosf(bd), ea * sinf(bd));
    }
}

// ---------------- K1: Bu = xbf(32768x256) @ Bmat(1024x256)^T -> Bu bf16 (32768x1024) ----------------
// Epilogue: C tile -> LDS -> coalesced Bu store (UNFIXED z-values) + fused per-chunk scan:
// full-chunk carry and 8 sub-chunk partial states U(c,q) per chain.
// __launch_bounds__(256,4): cap VGPR at 128 -> 4 blocks/CU (LDS 34KB x4 = 136 <= 160),
// halving k1's sequential rounds (2048 blocks: 4 rounds @2/CU -> 2 rounds @4/CU).
__global__ __launch_bounds__(256, 4) void k1_gemm(const unsigned short* __restrict__ A,
                                                  const unsigned short* __restrict__ Bm,
                                                  unsigned short* __restrict__ Bu,
                                                  const float2* __restrict__ Lbar,
                                                  float2* __restrict__ carry,
                                                  float2* __restrict__ Usub) {
    __shared__ unsigned short SH[16384];   // 32 KB: As=SH[0:8192], Bs=SH[8192:16384]; Cs overlays all
    __shared__ float2 Sbuf2[64][4];        // half-1 snapshots (3) + final (1) per chain
    int tid = threadIdx.x;
    int lane = tid & 63, wv = tid >> 6;          // 4 waves
    int wm = (wv >> 1) * 64, wn = (wv & 1) * 64; // 64x64 quadrant
    int Mb = blockIdx.x * 128, Nb = blockIdx.y * 128;
    int lr = lane >> 3;                 // row within 8-row chunk group
    int swz = ((lane & 7) ^ lr) * 8;    // swizzled source chunk (in shorts)
    f32x4 acc[4][4];
#pragma unroll
    for (int i = 0; i < 4; i++)
#pragma unroll
        for (int j = 0; j < 4; j++) acc[i][j] = (f32x4){0.f, 0.f, 0.f, 0.f};
    int mrow = lane & 15, quad = lane >> 4;
    for (int kb = 0; kb < 256; kb += 64) {
#pragma unroll
        for (int ch = wv; ch < 16; ch += 4) {
            int r = ch * 8 + lr;
            async_load16(A  + (size_t)(Mb + r) * 256 + kb + swz, (char*)SH + ch * 1024);
            async_load16(Bm + (size_t)(Nb + r) * 256 + kb + swz, (char*)SH + 16384 + ch * 1024);
        }
        __syncthreads();
#pragma unroll
        for (int kk = 0; kk < 64; kk += 32) {
            bf16x8 af[4], bfr[4];
#pragma unroll
            for (int i = 0; i < 4; i++) {
                int rr = wm + 16 * i + mrow;
                af[i] = *(const bf16x8*)&SH[rr * 64 + ((((kk >> 3) + quad) ^ (rr & 7)) << 3)];
            }
#pragma unroll
            for (int j = 0; j < 4; j++) {
                int rr = wn + 16 * j + mrow;
                bfr[j] = *(const bf16x8*)&SH[8192 + rr * 64 + ((((kk >> 3) + quad) ^ (rr & 7)) << 3)];
            }
#pragma unroll
            for (int i = 0; i < 4; i++)
#pragma unroll
                for (int j = 0; j < 4; j++)
                    acc[i][j] = __builtin_amdgcn_mfma_f32_16x16x32_bf16(af[i], bfr[j], acc[i][j], 0, 0, 0);
        }
        __syncthreads();
    }
    // ---- epilogue: C tile (128x128 bf16) into LDS ----
    unsigned short* Cs = SH;
#pragma unroll
    for (int i = 0; i < 4; i++)
#pragma unroll
        for (int j = 0; j < 4; j++)
#pragma unroll
            for (int r = 0; r < 4; r++) {
                int row = wm + 16 * i + quad * 4 + r;
                int col = wn + 16 * j + mrow;
                Cs[row * 128 + col] = f2bf(acc[i][j][r]);
            }
    __syncthreads();
    // coalesced Cs -> Bu (uint4 per thread, 8 iters) -- UNFIXED values
#pragma unroll
    for (int it = 0; it < 8; it++) {
        int o = tid * 16 + it * 4096;       // byte offset in Cs
        int row = o >> 8, colb = o & 255;
        uint4 v = *(const uint4*)((const char*)Cs + o);
        *(uint4*)((char*)Bu + (size_t)(Mb + row) * 2048 + (size_t)Nb * 2 + colb) = v;
    }
    // fused per-chunk scan: this block is chunk c of batch b, 64 complex chains.
    int d = Nb >> 9;
    int b = Mb >> 13;
    int c = (Mb >> 7) & 63;
    float2 s = make_float2(0.f, 0.f);
    float2 A2 = make_float2(0.f, 0.f);
    float2 snap[3];
    snap[0] = snap[1] = snap[2] = make_float2(0.f, 0.f);
    int p = 0;
    if (tid < 128) {
        int j = tid & 63, half = tid >> 6;
        p = ((Nb & 511) >> 1) + j;
        A2 = Lbar[d * 256 + p];
        const unsigned int* C32 = (const unsigned int*)Cs;
        int r0 = half * 64;
        if (d == 0) {
            for (int t = 0; t < 64; t++) {
                unsigned int v = C32[(r0 + t) * 64 + j];
                float2 z = make_float2(bf2f(v & 0xffffu), bf2f(v >> 16));
                s = cmad(A2, s, z);
                if ((t & 15) == 15 && t < 63) snap[t >> 4] = s;   // t=15,31,47 -> snap[0..2]
            }
        } else {
            for (int t = 63; t >= 0; t--) {
                unsigned int v = C32[(r0 + t) * 64 + j];
                float2 z = make_float2(bf2f(v & 0xffffu), bf2f(v >> 16));
                s = cmad(A2, s, z);
                if ((t & 15) == 0 && t > 0) snap[(t >> 4) - 1] = s;  // t=48,32,16 -> snap[2,1,0]
            }
        }
        if (half == 1) {
            Sbuf2[j][0] = snap[0]; Sbuf2[j][1] = snap[1];
            Sbuf2[j][2] = snap[2]; Sbuf2[j][3] = s;
        }
    }
    __syncthreads();
    if (tid < 64) {
        // own (half-0) state: fwd S0 (rows 0..63) / bwd S0' (rows 63..0 desc)
        float2 h1a = Sbuf2[tid][0], h1b = Sbuf2[tid][1], h1c = Sbuf2[tid][2], S1 = Sbuf2[tid][3];
        float2 a16 = A2;
#pragma unroll
        for (int k = 0; k < 4; k++) a16 = csq2(a16);
        float2 a32 = csq2(a16);
        float2 a48 = cmul2(a32, a16);
        float2 a64 = csq2(a32);
        float2 S0 = s;
        float2 Uq[8];
        float2 cfull;
        float2 zero = make_float2(0.f, 0.f);
        if (d == 0) {
            // U(q) = zero-init scan of rows [0,16q)
            Uq[0] = zero;  Uq[1] = snap[0]; Uq[2] = snap[1]; Uq[3] = snap[2];
            Uq[4] = S0;
            Uq[5] = cmad(a16, S0, h1a);   // rows[0,80)
            Uq[6] = cmad(a32, S0, h1b);
            Uq[7] = cmad(a48, S0, h1c);
            cfull = cmad(a64, S0, S1);
        } else {
            // bwd processes rows 127..0; U'(q) = zero-init scan of rows [16q+16,128)
            Uq[7] = zero;
            Uq[6] = h1c;   // rows[112,128)
            Uq[5] = h1b;   // rows[96,128)
            Uq[4] = h1a;   // rows[80,128)
            Uq[3] = S1;    // rows[64,128)
            Uq[2] = cmad(a16, S1, snap[2]);  // + rows[48,64)
            Uq[1] = cmad(a32, S1, snap[1]);
            Uq[0] = cmad(a48, S1, snap[0]);
            cfull = cmad(a64, S1, S0);
        }
        size_t cidx = ((size_t)(d * 4 + b) * NC + c) * 256 + p;
        carry[cidx] = cfull;
        size_t ub = (((size_t)(d * 4 + b) * NC + c) * 8) * 256 + p;
#pragma unroll
        for (int q = 0; q < 8; q++) Usub[ub + (size_t)q * 256] = Uq[q];
    }
}

// ---------------- K3 half: one K=512 GEMM in 4 BK=128 stages (r10-verbatim). Per stage:
// issue 64KB DMA -> __syncthreads (full drain) -> fix 64 chains (2 sequential 16-step
// units/thread) -> __syncthreads -> MFMA K=128 -> __syncthreads. Single-buffered; no DMA
// crosses a barrier interval; integer pack; MFMA accumulation order identical to r9.
static __device__ __forceinline__ void k3_half(const unsigned short* __restrict__ XS,
                                               const unsigned short* __restrict__ B3h,
                                               unsigned short* As, unsigned short* Bs,
                                               const float2* Ptab, const float2* LbarL,
                                               const float2* La16L,
                                               const float2* __restrict__ Uchunk,
                                               int Mb, int Hb, int coff, int d,
                                               int wm, int wn, int mrow, int quad,
                                               int wv, int lane, int tid,
                                               f32x4 (&acc)[4][4]) {
    int j = tid & 31, q = tid >> 5;
    int r0 = q * 16;
    const float2* ubase = Uchunk + q * 256 + j;   // U(q, p) = ubase[p - j]
    int lr4 = lane >> 4;            // row within 4-row 1KB chunk
    int lc = lane & 15;             // 16B chunk index within 256B row
    for (int st = 0; st < 4; st++) {
        int kb = st * 128;
        // ---- issue this stage's DMA (prev stage's MFMA reads ordered by trailing sync) ----
#pragma unroll
        for (int ch = wv; ch < 32; ch += 4) {
            int r = ch * 4 + lr4;
            int sw = (lc ^ (r & 15)) * 8;   // swizzled 16B source chunk (shorts)
            async_load16(XS + (size_t)(Mb + r) * 1024 + coff + kb + sw, (char*)As + ch * 1024);
        }
#pragma unroll
        for (int ch = wv; ch < 32; ch += 4) {
            int r = ch * 4 + lr4;
            int sw = (lc ^ (r & 15)) * 8;
            async_load16(B3h + (size_t)(Hb + r) * 512 + kb + sw, (char*)Bs + ch * 1024);
        }
        float2 Uc0 = ubase[kb >> 1];          // chains j and j+32 of this stage
        float2 Uc1 = ubase[(kb >> 1) + 32];   // (L2-resident; drained by sync)
        __syncthreads();   // tile ready for ALL waves (full vmcnt+lgkm drain + barrier)
        // ---- scan-fix the staged A tile: 2 sequential units (chains j, j+32) ----
        {
            unsigned int* A32 = (unsigned int*)As;
            int e = d ? (7 - q) : q;        // rows already processed = 16*e
#pragma unroll
            for (int u = 0; u < 2; u++) {
                int jj = j + u * 32;
                int p = (kb >> 1) + jj;
                float2 Ach = LbarL[d * 256 + p];
                float2 P  = Ptab[d * 256 + p];
                float2 bp = La16L[d * 256 + p];  // A^16
                float2 ap = make_float2(1.f, 0.f);
                if (e & 1) ap = cmul2(ap, bp);
                bp = csq2(bp);                   // A^32
                if (e & 2) ap = cmul2(ap, bp);
                bp = csq2(bp);                   // A^64
                if (e & 4) ap = cmul2(ap, bp);
                float2 sv = cmad(ap, P, u ? Uc1 : Uc0);  // entering state
                unsigned int zb[16];
#pragma unroll
                for (int tt = 0; tt < 16; tt++) {
                    int row = r0 + tt;
                    zb[tt] = A32[row * 64 + (((jj >> 2) ^ (row & 15)) << 2) + (jj & 3)];
                }
                if (d == 0) {
#pragma unroll
                    for (int tt = 0; tt < 16; tt++) {
                        float2 z = make_float2(bits2f(zb[tt] << 16), bits2f(zb[tt] & 0xffff0000u));
                        sv = cmad(Ach, sv, z);
                        zb[tt] = pack_bf16i(sv.x, sv.y);
                    }
                } else {
#pragma unroll
                    for (int tt = 15; tt >= 0; tt--) {
                        float2 z = make_float2(bits2f(zb[tt] << 16), bits2f(zb[tt] & 0xffff0000u));
                        sv = cmad(Ach, sv, z);
                        zb[tt] = pack_bf16i(sv.x, sv.y);
                    }
                }
#pragma unroll
                for (int tt = 0; tt < 16; tt++) {
                    int row = r0 + tt;
                    A32[row * 64 + (((jj >> 2) ^ (row & 15)) << 2) + (jj & 3)] = zb[tt];
                }
            }
        }
        __syncthreads();   // fix visible to all waves
        // ---- MFMA on fixed tile: K=128 (same per-acc K-order as r9) ----
#pragma unroll
        for (int kk = 0; kk < 128; kk += 32) {
            bf16x8 af[4], bfr[4];
#pragma unroll
            for (int i = 0; i < 4; i++) {
                int rr = wm + 16 * i + mrow;
                af[i] = *(const bf16x8*)&As[rr * 128 + ((((kk >> 3) + quad) ^ (rr & 15)) << 3)];
            }
#pragma unroll
            for (int jj2 = 0; jj2 < 4; jj2++) {
                int rr = wn + 16 * jj2 + mrow;
                bfr[jj2] = *(const bf16x8*)&Bs[rr * 128 + ((((kk >> 3) + quad) ^ (rr & 15)) << 3)];
            }
#pragma unroll
            for (int i = 0; i < 4; i++)
#pragma unroll
                for (int jj2 = 0; jj2 < 4; jj2++)
                    acc[i][jj2] = __builtin_amdgcn_mfma_f32_16x16x32_bf16(af[i], bfr[jj2], acc[i][jj2], 0, 0, 0);
        }
        __syncthreads();   // MFMA reads done before next stage's DMA overwrites
    }
}

// ---------------- K3: out = gelu(xs_f·Cf + Df*x) + gelu(xs_b·Cb + Db*x) with fused scan fix ----------------
__global__ __launch_bounds__(256, 2) void k3_gemm(const unsigned short* __restrict__ XS,
                                                  const unsigned short* __restrict__ B3,
                                                  const unsigned short* __restrict__ xbf,
                                                  const float* __restrict__ Df,
                                                  const float* __restrict__ Db,
                                                  const float2* __restrict__ Lbar,
                                                  const float2* __restrict__ carry,
                                                  const float2* __restrict__ Usub,
                                                  float* __restrict__ out) {
    __shared__ unsigned short As[16384], Bs[16384];   // 32 KB single-buffered BK=128 tiles
    __shared__ float2 Ptab[512];    // chunk-entry prefix states (d*256+p)
    __shared__ float2 LbarL[512];
    __shared__ float2 La16L[512];   // A^16 per (d,p) -- captured mid-prefix for free
    int tid = threadIdx.x;
    int lane = tid & 63, wv = tid >> 6;          // 4 waves
    int wm = (wv >> 1) * 64, wn = (wv & 1) * 64; // 64x64 quadrant
    int Mb = blockIdx.x * 128, Hb = blockIdx.y * 128;
    int b = Mb >> 13, c = (Mb >> 7) & 63;
    int mrow = lane & 15, quad = lane >> 4;
    // ---- chunk-entry prefix: combine <=63 chunk carries (L2-resident, loads pipelined) ----
    {
        int p0 = tid;
#pragma unroll
        for (int d2 = 0; d2 < 2; d2++) {
            float2 A = Lbar[d2 * 256 + p0];
            LbarL[d2 * 256 + p0] = A;
            float2 apow = A;
#pragma unroll
            for (int k = 0; k < 4; k++) apow = csq2(apow);   // A^16
            La16L[d2 * 256 + p0] = apow;
#pragma unroll
            for (int k = 0; k < 3; k++) apow = csq2(apow);   // A^128
            float2 a128 = apow;
            float2 s = make_float2(0.f, 0.f);
            const float2* cb = carry + ((size_t)(d2 * 4 + b) * NC) * 256 + p0;
            if (d2 == 0) {
#pragma unroll 16
                for (int jj = 0; jj < c; jj++) s = cmad(a128, s, cb[(size_t)jj * 256]);
            } else {
#pragma unroll 16
                for (int jj = NC - 1; jj > c; jj--) s = cmad(a128, s, cb[(size_t)jj * 256]);
            }
            Ptab[d2 * 256 + p0] = s;
        }
    }
    __syncthreads();
    f32x4 accf[4][4], accb[4][4];
#pragma unroll
    for (int i = 0; i < 4; i++)
#pragma unroll
        for (int j = 0; j < 4; j++) {
            accf[i][j] = (f32x4){0.f, 0.f, 0.f, 0.f};
            accb[i][j] = (f32x4){0.f, 0.f, 0.f, 0.f};
        }
    const float2* U0 = Usub + (((size_t)(0 * 4 + b) * NC + c) * 8) * 256;
    const float2* U1 = Usub + (((size_t)(1 * 4 + b) * NC + c) * 8) * 256;
    // forward half (k-cols 0..511), then backward half (512..1023) — statically bound accs
    k3_half(XS, B3,          As, Bs, Ptab, LbarL, La16L, U0, Mb, Hb, 0,   0,
            wm, wn, mrow, quad, wv, lane, tid, accf);
    k3_half(XS, B3 + 131072, As, Bs, Ptab, LbarL, La16L, U1, Mb, Hb, 512, 1,
            wm, wn, mrow, quad, wv, lane, tid, accb);
#pragma unroll
    for (int i = 0; i < 4; i++)
#pragma unroll
        for (int j = 0; j < 4; j++) {
            int h = Hb + wn + 16 * j + mrow;
            float df = Df[h], db = Db[h];
#pragma unroll
            for (int r = 0; r < 4; r++) {
                int row = Mb + wm + 16 * i + quad * 4 + r;
                float xv = bf2f((unsigned int)xbf[(size_t)row * 256 + h]);
                float yf = accf[i][j][r] + df * xv;
                float yb = accb[i][j][r] + db * xv;
                out[(size_t)row * 256 + h] = gelu_f(yf) + gelu_f(yb);
            }
        }
}

// ---------------- launcher ----------------
extern "C" void kernel_launch(void* const* d_in, const int* in_sizes, int n_in,
                              void* d_out, int out_size, void* d_ws, size_t ws_size,
                              hipStream_t stream) {
    const float* x   = (const float*)d_in[0];
    const float* fLr = (const float*)d_in[1];
    const float* fIm = (const float*)d_in[2];
    const float* fLd = (const float*)d_in[3];
    const float* fBr = (const float*)d_in[4];
    const float* fBi = (const float*)d_in[5];
    const float* fCr = (const float*)d_in[6];
    const float* fCi = (const float*)d_in[7];
    const float* fD  = (const float*)d_in[8];
    const float* bLr = (const float*)d_in[9];
    const float* bIm = (const float*)d_in[10];
    const float* bLd = (const float*)d_in[11];
    const float* bBr = (const float*)d_in[12];
    const float* bBi = (const float*)d_in[13];
    const float* bCr = (const float*)d_in[14];
    const float* bCi = (const float*)d_in[15];
    const float* bD  = (const float*)d_in[16];
    float* out = (float*)d_out;

    char* ws = (char*)d_ws;
    unsigned short* xbf  = (unsigned short*)(ws);                               // 16 MiB
    unsigned short* Bu   = (unsigned short*)(ws + 16777216);                    // 64 MiB (unfixed z)
    unsigned short* Bmat = (unsigned short*)(ws + 16777216 + 67108864);         // 512 KiB
    unsigned short* B3   = (unsigned short*)(ws + 16777216 + 67108864 + 524288);// 512 KiB
    float2* LbarWS = (float2*)(ws + 16777216 + 67108864 + 1048576);             // 4 KiB
    float2* carry  = (float2*)(ws + 16777216 + 67108864 + 1048576 + 4096);      // 1 MiB
    float2* Usub   = (float2*)(ws + 16777216 + 67108864 + 1048576 + 4096 + 1048576); // 8 MiB

    prep_kernel<<<10242, 256, 0, stream>>>(fLr, fIm, fLd, fBr, fBi, fCr, fCi,
                                           bLr, bIm, bLd, bBr, bBi, bCr, bCi,
                                           (const float4*)x, (ushort4*)xbf,
                                           Bmat, B3, LbarWS);
    k1_gemm<<<dim3(256, 8), 256, 0, stream>>>(xbf, Bmat, Bu, LbarWS, carry, Usub);
    k3_gemm<<<dim3(256, 2), 256, 0, stream>>>(Bu, B3, xbf, fD, bD, LbarWS, carry, Usub, out);
}